// Round 1
// baseline (46.643 us; speedup 1.0000x reference)
//
#include <hip/hip_runtime.h>

#define NQ 12
#define DIM 4096          // 2^12 amplitudes
#define DEPTH 4
#define BLK 256
#define PER (DIM / BLK)   // 16 amplitudes per thread
#define PAIRS (DIM / 2)
#define PPT (PAIRS / BLK) // 8 pairs per thread

// inverse Gray code on 12 bits: bit p of result = XOR of bits >= p of v.
// This is the whole CNOT chain CNOT(0,1)...CNOT(10,11) as one permutation:
// new_state[igray12(src)] = old_state[src].
__device__ __forceinline__ int igray12(int v) {
    v ^= v >> 1;
    v ^= v >> 2;
    v ^= v >> 4;
    v ^= v >> 8;
    return v & (DIM - 1);
}

__global__ __launch_bounds__(BLK, 2)
void qsim_kernel(const float* __restrict__ x,
                 const float* __restrict__ rys,
                 float* __restrict__ out) {
    __shared__ __align__(16) float2 buf[DIM];   // 32 KB state
    __shared__ float cx[NQ], sx[NQ];            // RX cos/sin (per batch)
    __shared__ float cr[DEPTH * NQ], sr[DEPTH * NQ]; // RY cos/sin (shared)
    __shared__ float zred[4][NQ];

    const int b = blockIdx.x;
    const int t = threadIdx.x;

    if (t < NQ) {
        float th = 0.5f * x[b * NQ + t];
        cx[t] = cosf(th);
        sx[t] = sinf(th);
    } else if (t >= 64 && t < 64 + DEPTH * NQ) {
        int i = t - 64;
        float th = 0.5f * rys[i];
        cr[i] = cosf(th);
        sr[i] = sinf(th);
    }
    __syncthreads();

    // ---- RX layer on |0...0> is a product state: build it directly. ----
    // qubit q lives at bit position p = 11-q (stride 2^p).
    // amp(m) = prod_p (bit ? sin : cos) * (-i)^popcount(m)
    for (int r = 0; r < PER; ++r) {
        int m = t + r * BLK;
        float mag = 1.0f;
        #pragma unroll
        for (int p = 0; p < NQ; ++p) {
            mag *= ((m >> p) & 1) ? sx[NQ - 1 - p] : cx[NQ - 1 - p];
        }
        int pc = __popc(m) & 3;
        float2 a;
        a.x = (pc == 0) ? mag : ((pc == 2) ? -mag : 0.0f);
        a.y = (pc == 1) ? -mag : ((pc == 3) ? mag : 0.0f);
        buf[m] = a;
    }

    for (int d = 0; d < DEPTH; ++d) {
        #pragma unroll
        for (int q = 0; q < NQ; ++q) {
            const float c = cr[d * NQ + q];
            const float s = sr[d * NQ + q];
            const int p = NQ - 1 - q;       // bit position / log2 stride
            __syncthreads();
            if (p == 0) {
                // adjacent pairs: one float4 per pair, bank-conflict-free
                #pragma unroll
                for (int r = 0; r < PPT; ++r) {
                    int j = t + r * BLK;
                    float4 v = *reinterpret_cast<float4*>(&buf[2 * j]);
                    float4 nv;
                    nv.x = c * v.x - s * v.z;
                    nv.y = c * v.y - s * v.w;
                    nv.z = s * v.x + c * v.z;
                    nv.w = s * v.y + c * v.w;
                    *reinterpret_cast<float4*>(&buf[2 * j]) = nv;
                }
            } else {
                const int mask = (1 << p) - 1;
                #pragma unroll
                for (int r = 0; r < PPT; ++r) {
                    int j = t + r * BLK;
                    int i0 = ((j & ~mask) << 1) | (j & mask);
                    int i1 = i0 + (1 << p);
                    float2 a0 = buf[i0];
                    float2 a1 = buf[i1];
                    float2 n0 = { c * a0.x - s * a1.x, c * a0.y - s * a1.y };
                    float2 n1 = { s * a0.x + c * a1.x, s * a0.y + c * a1.y };
                    buf[i0] = n0;
                    buf[i1] = n1;
                }
            }
        }
        // ---- CNOT chain as one in-place permutation (register staged) ----
        __syncthreads();
        float2 va[PER];
        #pragma unroll
        for (int r = 0; r < PER; ++r) va[r] = buf[t + r * BLK];
        __syncthreads();
        #pragma unroll
        for (int r = 0; r < PER; ++r) {
            int src = t + r * BLK;
            buf[igray12(src)] = va[r];   // bijective within 64-aligned blocks
        }
    }

    // ---- Z expectations: z_q = sum_m |amp|^2 * (1 - 2*bit(m, 11-q)) ----
    __syncthreads();
    float z[NQ];
    #pragma unroll
    for (int q = 0; q < NQ; ++q) z[q] = 0.0f;
    for (int r = 0; r < PER; ++r) {
        int m = t + r * BLK;
        float2 a = buf[m];
        float pr = a.x * a.x + a.y * a.y;
        #pragma unroll
        for (int q = 0; q < NQ; ++q)
            z[q] += ((m >> (NQ - 1 - q)) & 1) ? -pr : pr;
    }
    #pragma unroll
    for (int q = 0; q < NQ; ++q) {
        #pragma unroll
        for (int off = 32; off > 0; off >>= 1)
            z[q] += __shfl_down(z[q], off, 64);
    }
    const int wave = t >> 6, lane = t & 63;
    if (lane == 0) {
        #pragma unroll
        for (int q = 0; q < NQ; ++q) zred[wave][q] = z[q];
    }
    __syncthreads();
    if (t < NQ) {
        out[b * NQ + t] = zred[0][t] + zred[1][t] + zred[2][t] + zred[3][t];
    }
}

extern "C" void kernel_launch(void* const* d_in, const int* in_sizes, int n_in,
                              void* d_out, int out_size, void* d_ws, size_t ws_size,
                              hipStream_t stream) {
    const float* x   = (const float*)d_in[0];
    const float* rys = (const float*)d_in[1];
    // d_in[2] (cnot_params) is unused by the reference — CNOT takes no params.
    float* out = (float*)d_out;
    qsim_kernel<<<512, BLK, 0, stream>>>(x, rys, out);
}